// Round 6
// baseline (943.149 us; speedup 1.0000x reference)
//
#include <hip/hip_runtime.h>

// FFT-based causal long convolution for (b=4, l=8192, d=1024) fp32.
// One workgroup per (b, d) pair. Real FFT of N=16384 as complex FFT of M=8192
// via even/odd packing. 32 KB LDS batch buffer (half-spectrum at a time).
//
// vs round 5 (spill regression at VGPR=64):
//  - __attribute__((amdgpu_waves_per_eu(4,4))): round 5's launch_bounds(.,4)
//    only set MIN waves/EU; LLVM's occupancy heuristic targeted 8 waves/EU
//    (64-VGPR budget) and spilled the ~120-reg live set -> 1.9 GB scratch
//    traffic, HBM-bound. Pinning min=max=4 gives a 128-VGPR budget.
//  - Register demand cut: p[32] (64 persistent VGPRs) replaced by xv[16] +
//    factorized first/last pass. With zero-padding, stage 0 of the 5-stage
//    pass makes lower=xv, upper=xv*w0*cr(t); stages 1-4 act within each
//    16-half and equal fft4_regs(q, w0^2) exactly (twiddle chain matches).
//    Batch 1 (odd k) runs first while xv persists; batch 0 consumes xv
//    in place; final inverse recombines y = q0 + w0i*cr(t)*q1.
//    Peak live set ~90 VGPR.
//  - Unchanged: batched middle section in 32 KB LDS (round-5 verified math),
//    per-d filter spectrum precompute, load-in-loop spectral multiply,
//    bijective XCD swizzle, swz() LDS bank swizzle.

#define M 8192
#define NTH 256
#define MAXP 17           // fallback kernel only

__device__ __forceinline__ float2 cadd(float2 a, float2 b){ return make_float2(a.x+b.x, a.y+b.y); }
__device__ __forceinline__ float2 csub(float2 a, float2 b){ return make_float2(a.x-b.x, a.y-b.y); }
__device__ __forceinline__ float2 cmul(float2 a, float2 b){ return make_float2(a.x*b.x - a.y*b.y, a.x*b.y + a.y*b.x); }
__device__ __forceinline__ float2 conjf2(float2 a){ return make_float2(a.x, -a.y); }
__device__ __forceinline__ int rev13(int k){ return (int)(__brev((unsigned)k) >> 19); }
__device__ __forceinline__ int swz(int e){ return e ^ ((e >> 4) & 15) ^ ((e >> 8) & 15); }

static __device__ const float PI_F = 3.14159265358979323846f;

// cos/sin(pi*u/16); indexed with compile-time u in fully unrolled loops.
constexpr float CR_C[17] = {
  1.f, 0.98078528f, 0.92387953f, 0.83146961f, 0.70710678f,
  0.55557023f, 0.38268343f, 0.19509032f, 0.f, -0.19509032f,
  -0.38268343f, -0.55557023f, -0.70710678f, -0.83146961f,
  -0.92387953f, -0.98078528f, -1.f };
constexpr float CR_S[17] = {
  0.f, 0.19509032f, 0.38268343f, 0.55557023f, 0.70710678f,
  0.83146961f, 0.92387953f, 0.98078528f, 1.f, 0.98078528f,
  0.92387953f, 0.83146961f, 0.70710678f, 0.55557023f,
  0.38268343f, 0.19509032f, 0.f };

// a * e^{-i*pi*idx/16} (fwd) or a * e^{+i*pi*idx/16} (inv); idx compile-time.
__device__ __forceinline__ float2 cmul_cr(float2 a, int idx, bool inv) {
  if (idx == 0) return a;
  const float c = CR_C[idx], s = CR_S[idx];
  if (!inv) return make_float2(a.x*c + a.y*s, a.y*c - a.x*s);
  return make_float2(a.x*c - a.y*s, a.x*s + a.y*c);
}

// ---------------- 16-point fused 4-stage networks --------------------------
// Forward: halves 8W..W (W = group stride context); base twiddle w0, chain
// w[st] = w0^(2^st), cr idx u*(16/D). Inverse: conjugate ladder.
template<bool INV>
__device__ __forceinline__ void fft4_regs(float2 (&p)[16], float2 w0) {
  float2 w[4];
  w[0] = w0;
  w[1] = cmul(w[0], w[0]);
  w[2] = cmul(w[1], w[1]);
  w[3] = cmul(w[2], w[2]);
  if (!INV) {
#pragma unroll
    for (int st = 0; st < 4; ++st) {
      const int D = 8 >> st;
#pragma unroll
      for (int t0 = 0; t0 < 16; ++t0) {
        if ((t0 & D) == 0) {
          const int u = t0 & (D - 1);
          float2 a = p[t0], b = p[t0 + D];
          p[t0] = cadd(a, b);
          p[t0 + D] = cmul_cr(cmul(csub(a, b), w[st]), u * (16 / D), false);
        }
      }
    }
  } else {
#pragma unroll
    for (int st = 0; st < 4; ++st) {
      const int D = 1 << st;
#pragma unroll
      for (int t0 = 0; t0 < 16; ++t0) {
        if ((t0 & D) == 0) {
          const int u = t0 & (D - 1);
          float2 b = cmul_cr(cmul(p[t0 + D], w[3 - st]), u * (16 / D), true);
          float2 a = p[t0];
          p[t0] = cadd(a, b);
          p[t0 + D] = csub(a, b);
        }
      }
    }
  }
}

// Contiguous 16-pt groups (r=0): fwd halves 8..1, inv halves 1..8. No sincos.
template<bool INV>
__device__ __forceinline__ void fft4c_regs(float2 (&p)[16]) {
  if (!INV) {
#pragma unroll
    for (int st = 0; st < 4; ++st) {
      const int D = 8 >> st;
#pragma unroll
      for (int t0 = 0; t0 < 16; ++t0) {
        if ((t0 & D) == 0) {
          const int u = t0 & (D - 1);
          float2 a = p[t0], b = p[t0 + D];
          p[t0] = cadd(a, b);
          p[t0 + D] = cmul_cr(csub(a, b), u * (16 / D), false);
        }
      }
    }
  } else {
#pragma unroll
    for (int st = 0; st < 4; ++st) {
      const int D = 1 << st;
#pragma unroll
      for (int t0 = 0; t0 < 16; ++t0) {
        if ((t0 & D) == 0) {
          const int u = t0 & (D - 1);
          float2 b = cmul_cr(p[t0 + D], u * (16 / D), true);
          float2 a = p[t0];
          p[t0] = cadd(a, b);
          p[t0 + D] = csub(a, b);
        }
      }
    }
  }
}

// Stride-16 pass over the 4096-pt batch buffer. 256 groups = 256 threads.
template<bool INV>
__device__ __forceinline__ void pass_s16(float2* LB, int tid) {
  const int r = tid & 15, gl = tid >> 4;
  const int base = gl * 256 + r;
  float2 q[16];
#pragma unroll
  for (int t = 0; t < 16; ++t) q[t] = LB[swz(base + 16 * t)];
  float s, c;
  const float th = PI_F * (float)r * (1.0f / 128.0f);
  __sincosf(INV ? th : -th, &s, &c);
  fft4_regs<INV>(q, make_float2(c, s));
#pragma unroll
  for (int t = 0; t < 16; ++t) LB[swz(base + 16 * t)] = q[t];
}

// Contiguous pass over the 4096-pt batch buffer. 256 groups = 256 threads.
template<bool INV>
__device__ __forceinline__ void pass_c16(float2* LB, int tid) {
  const int base = tid * 16;
  float2 q[16];
#pragma unroll
  for (int t = 0; t < 16; ++t) q[t] = LB[swz(base + t)];
  fft4c_regs<INV>(q);
#pragma unroll
  for (int t = 0; t < 16; ++t) LB[swz(base + t)] = q[t];
}

// Spectral multiply for one parity batch (HALF=0: even k; HALF=1: odd k).
template<int HALF>
__device__ __forceinline__ void spec_mult(float2* LB, int tid,
                                          const float4* kfp) {
  constexpr int NQ = (HALF == 0) ? 9 : 8;
#pragma unroll
  for (int q = 0; q < NQ; ++q) {
    int kp = tid + 256 * q;
    int k = 2 * kp + HALF;
    if (k <= M / 2) {
      float4 kv = kfp[k];                    // short-lived, per-iteration
      int rk  = rev13(k) - HALF * 4096;      // local position in batch
      int rmk = rev13((M - k) & (M - 1)) - HALF * 4096;
      float2 Zk = LB[swz(rk)], Zmk = LB[swz(rmk)];
      float2 Ze = make_float2(0.5f*(Zk.x + Zmk.x), 0.5f*(Zk.y - Zmk.y));
      float2 t  = make_float2(Zk.x - Zmk.x, Zk.y + Zmk.y);
      float2 Zo = make_float2(0.5f*t.y, -0.5f*t.x);
      float s, c; __sincosf(-PI_F * (float)k * (1.0f/(float)M), &s, &c);
      float2 W = make_float2(c, s);
      float2 WZo = cmul(W, Zo);
      float2 Uk  = cadd(Ze, WZo);
      float2 Umk = conjf2(csub(Ze, WZo));
      float2 Yk  = cmul(Uk,  make_float2(kv.x, kv.y));
      float2 Ymk = cmul(Umk, make_float2(kv.z, kv.w));
      float2 Ye  = make_float2(0.5f*(Yk.x + Ymk.x), 0.5f*(Yk.y - Ymk.y));
      float2 t2  = make_float2(0.5f*(Yk.x - Ymk.x), 0.5f*(Yk.y + Ymk.y));
      float2 Zoy = cmul(conjf2(W), t2);
      float2 Zyk  = make_float2(Ye.x - Zoy.y, Ye.y + Zoy.x);
      float2 Zymk = make_float2(Ye.x + Zoy.y, Zoy.x - Ye.y);
      LB[swz(rk)]  = Zyk;
      LB[swz(rmk)] = Zymk;                   // k==0 / k==4096: same slot, same value
    }
  }
}

// Spectrum extract (filter) for one parity batch.
template<int HALF>
__device__ __forceinline__ void spec_extract(float2* LB, int tid,
                                             float4* out) {
  constexpr int NQ = (HALF == 0) ? 9 : 8;
#pragma unroll
  for (int q = 0; q < NQ; ++q) {
    int kp = tid + 256 * q;
    int k = 2 * kp + HALF;
    if (k <= M / 2) {
      int rk  = rev13(k) - HALF * 4096;
      int rmk = rev13((M - k) & (M - 1)) - HALF * 4096;
      float2 Zk = LB[swz(rk)], Zmk = LB[swz(rmk)];
      float2 Ze = make_float2(0.5f*(Zk.x + Zmk.x), 0.5f*(Zk.y - Zmk.y));
      float2 t  = make_float2(Zk.x - Zmk.x, Zk.y + Zmk.y);
      float2 Zo = make_float2(0.5f*t.y, -0.5f*t.x);
      float s, c; __sincosf(-PI_F * (float)k * (1.0f/(float)M), &s, &c);
      float2 W = make_float2(c, s);
      float2 WZo = cmul(W, Zo);
      float2 Kk = cadd(Ze, WZo);
      float2 Km = conjf2(csub(Ze, WZo));
      out[k] = make_float4(Kk.x, Kk.y, Km.x, Km.y);
    }
  }
}

// Forward middle: batch data in LB -> spectrum (bit-reversed) in LB.
__device__ __forceinline__ void fwd_middle(float2* LB, int tid) {
  pass_s16<false>(LB, tid);                  // halves 128..16
  __syncthreads();
  pass_c16<false>(LB, tid);                  // halves 8..1
  __syncthreads();
}

// Inverse middle: spectrum in LB -> batch data in LB.
__device__ __forceinline__ void inv_middle(float2* LB, int tid) {
  pass_c16<true>(LB, tid);                   // halves 1..8
  __syncthreads();
  pass_s16<true>(LB, tid);                   // halves 16..128
  __syncthreads();
}

// Precompute per-d filter spectrum: (K[k], K[M-k]) for k=0..M/2 as float4.
__global__ __launch_bounds__(NTH)
__attribute__((amdgpu_waves_per_eu(4, 4)))
void filt_fft_kernel(const float* __restrict__ filt, float4* __restrict__ kf) {
  __shared__ float2 LB[4096];                // 32 KB
  const int tid = threadIdx.x;
  const int d = blockIdx.x;
  const float* fp = filt + (size_t)d * 8192;
  float4* out = kf + (size_t)d * (M/2 + 1);

  float2 xv[16];
#pragma unroll
  for (int t = 0; t < 16; ++t) {
    int m = tid + t * NTH;
    xv[t] = make_float2(fp[2*m], fp[2*m + 1]);
  }
  float s, c;
  __sincosf(-PI_F * (float)tid * (1.0f / 4096.0f), &s, &c);
  const float2 w0f = make_float2(c, s);
  const float2 w0fsq = cmul(w0f, w0f);

  // ---- batch 1 (odd k, upper half): q = xv * w0f * cr(t), then 4 stages ---
  {
    float2 q[16];
#pragma unroll
    for (int t = 0; t < 16; ++t) q[t] = cmul_cr(cmul(xv[t], w0f), t, false);
    fft4_regs<false>(q, w0fsq);
#pragma unroll
    for (int g = 0; g < 16; ++g) LB[swz(g * 256 + tid)] = q[g];
  }
  __syncthreads();
  fwd_middle(LB, tid);
  spec_extract<1>(LB, tid, out);
  __syncthreads();

  // ---- batch 0 (even k, lower half): xv in place ----
  fft4_regs<false>(xv, w0fsq);
#pragma unroll
  for (int g = 0; g < 16; ++g) LB[swz(g * 256 + tid)] = xv[g];
  __syncthreads();
  fwd_middle(LB, tid);
  spec_extract<0>(LB, tid, out);
}

// ---------------- HOT KERNEL: requires kf ----------------------------------
__global__ __launch_bounds__(NTH)
__attribute__((amdgpu_waves_per_eu(4, 4)))
void longconv_kf_kernel(const float* __restrict__ x,
                        const float4* __restrict__ kf,
                        float* __restrict__ y) {
  __shared__ float2 LB[4096];                // 32 KB
  const int tid = threadIdx.x;

  // Bijective XCD swizzle: XCD j owns 512 consecutive blk -> co-resident
  // blocks share x/y cache lines in its private L2.
  const int nwg = gridDim.x;                 // 4096, multiple of 8
  const int cpx = nwg >> 3;
  const int bid = blockIdx.x;
  const int blk = (bid & 7) * cpx + (bid >> 3);
  const int d = blk & 1023;
  const int b = blk >> 10;

  const float4* kfp = kf + (size_t)d * (M/2 + 1);

  // ---- load x (strided 4B/4KB; lines merged across blocks in L2) ----------
  float2 xv[16];
  {
    const float* xp = x + (size_t)b * (8192 * 1024) + d;
#pragma unroll
    for (int t = 0; t < 16; ++t) {
      int m = tid + t * NTH;
      xv[t] = make_float2(xp[(size_t)(2*m)     * 1024],
                          xp[(size_t)(2*m + 1) * 1024]);
    }
  }
  float s, c;
  __sincosf(-PI_F * (float)tid * (1.0f / 4096.0f), &s, &c);
  const float2 w0f = make_float2(c, s);
  const float2 w0fsq = cmul(w0f, w0f);

  // ---- batch 1 (odd k, upper half) first: q built from xv, xv persists ----
  float2 q1[16];
#pragma unroll
  for (int t = 0; t < 16; ++t) q1[t] = cmul_cr(cmul(xv[t], w0f), t, false);
  fft4_regs<false>(q1, w0fsq);
#pragma unroll
  for (int g = 0; g < 16; ++g) LB[swz(g * 256 + tid)] = q1[g];
  __syncthreads();
  fwd_middle(LB, tid);
  spec_mult<1>(LB, tid, kfp);
  __syncthreads();
  inv_middle(LB, tid);
#pragma unroll
  for (int g = 0; g < 16; ++g) q1[g] = LB[swz(g * 256 + tid)];
  __syncthreads();                           // LB reads done before batch 0

  // ---- batch 0 (even k, lower half): xv consumed in place -----------------
  fft4_regs<false>(xv, w0fsq);
#pragma unroll
  for (int g = 0; g < 16; ++g) LB[swz(g * 256 + tid)] = xv[g];
  __syncthreads();
  fwd_middle(LB, tid);
  spec_mult<0>(LB, tid, kfp);
  __syncthreads();
  inv_middle(LB, tid);
#pragma unroll
  for (int g = 0; g < 16; ++g) xv[g] = LB[swz(g * 256 + tid)];

  // ---- final inverse (halves 256..4096) + recombine + store y -------------
  {
    float si, ci;
    __sincosf(PI_F * (float)tid * (1.0f / 4096.0f), &si, &ci);
    const float2 w0i = make_float2(ci, si);
    const float2 w0isq = cmul(w0i, w0i);
    fft4_regs<true>(xv, w0isq);              // lower-half inverse stages
    fft4_regs<true>(q1, w0isq);              // upper-half inverse stages
    float* yp = y + (size_t)b * (8192 * 1024) + d;
    const float inv = 1.0f / (float)M;
#pragma unroll
    for (int t = 0; t < 16; ++t) {
      // final stage (D=16): lower output only (upper not needed for y)
      float2 bq = cmul_cr(cmul(q1[t], w0i), t, true);
      float2 v = cadd(xv[t], bq);
      int m = tid + t * NTH;                 // first l samples (packed pairs)
      yp[(size_t)(2*m)     * 1024] = v.x * inv;
      yp[(size_t)(2*m + 1) * 1024] = v.y * inv;
    }
  }
}

// ---------------- FALLBACK: no workspace (64 KB LDS, round-4 structure) ----
template<int HS, bool INV, bool FIRST_PAD, bool LAST_HALF>
__device__ __forceinline__ void fft5_regs(float2 (&p)[32], int r) {
  float s, c;
  const float th = PI_F * (float)r * (1.0f / (16.0f * (float)HS));
  __sincosf(INV ? th : -th, &s, &c);
  float2 w[5];
  w[0] = make_float2(c, s);
  w[1] = cmul(w[0], w[0]);
  w[2] = cmul(w[1], w[1]);
  w[3] = cmul(w[2], w[2]);
  w[4] = cmul(w[3], w[3]);
  if (!INV) {
#pragma unroll
    for (int st = 0; st < 5; ++st) {
      const int D = 16 >> st;
#pragma unroll
      for (int t0 = 0; t0 < 32; ++t0) {
        if ((t0 & D) == 0) {
          const int u = t0 & (D - 1);
          float2 a = p[t0];
          if (FIRST_PAD && st == 0) {
            p[t0 + D] = cmul_cr(cmul(a, w[0]), u, false);
          } else {
            float2 b = p[t0 + D];
            p[t0] = cadd(a, b);
            p[t0 + D] = cmul_cr(cmul(csub(a, b), w[st]), u * (16 / D), false);
          }
        }
      }
    }
  } else {
#pragma unroll
    for (int st = 0; st < 5; ++st) {
      const int D = 1 << st;
#pragma unroll
      for (int t0 = 0; t0 < 32; ++t0) {
        if ((t0 & D) == 0) {
          const int u = t0 & (D - 1);
          float2 b = cmul_cr(cmul(p[t0 + D], w[4 - st]), u * (16 / D), true);
          float2 a = p[t0];
          p[t0] = cadd(a, b);
          if (!(LAST_HALF && st == 4)) p[t0 + D] = csub(a, b);
        }
      }
    }
  }
}

template<bool INV>
__device__ __forceinline__ void pass5_lds(float2* L, int tid) {
  const int r = tid & 7;
  const int base = ((tid - r) << 5) + r;
  float2 p[32];
#pragma unroll
  for (int t = 0; t < 32; ++t) p[t] = L[swz(base + t * 8)];
  fft5_regs<8, INV, false, false>(p, r);
#pragma unroll
  for (int t = 0; t < 32; ++t) L[swz(base + t * 8)] = p[t];
}

template<bool INV>
__device__ __forceinline__ void pass3_lds(float2* L, int tid) {
#pragma unroll
  for (int g = 0; g < 4; ++g) {
    const int base = tid * 32 + g * 8;
    float2 p[8];
#pragma unroll
    for (int t = 0; t < 8; ++t) p[t] = L[swz(base + t)];
    if (!INV) {
#pragma unroll
      for (int st = 0; st < 3; ++st) {
        const int D = 4 >> st;
#pragma unroll
        for (int t0 = 0; t0 < 8; ++t0) {
          if ((t0 & D) == 0) {
            const int u = t0 & (D - 1);
            float2 a = p[t0], b = p[t0 + D];
            p[t0] = cadd(a, b);
            p[t0 + D] = cmul_cr(csub(a, b), u * (16 / D), false);
          }
        }
      }
    } else {
#pragma unroll
      for (int st = 0; st < 3; ++st) {
        const int D = 1 << st;
#pragma unroll
        for (int t0 = 0; t0 < 8; ++t0) {
          if ((t0 & D) == 0) {
            const int u = t0 & (D - 1);
            float2 b = cmul_cr(p[t0 + D], u * (16 / D), true);
            float2 a = p[t0];
            p[t0] = cadd(a, b);
            p[t0 + D] = csub(a, b);
          }
        }
      }
    }
#pragma unroll
    for (int t = 0; t < 8; ++t) L[swz(base + t)] = p[t];
  }
}

__global__ __launch_bounds__(NTH, 2)
void longconv_fallback_kernel(const float* __restrict__ x,
                              const float* __restrict__ filt,
                              float* __restrict__ y) {
  __shared__ float2 L[M];
  const int tid = threadIdx.x;
  const int nwg = gridDim.x;
  const int cpx = nwg >> 3;
  const int bid = blockIdx.x;
  const int blk = (bid & 7) * cpx + (bid >> 3);
  const int d = blk & 1023;
  const int b = blk >> 10;

  float2 Kk[MAXP], Kmk[MAXP];

  {
    const float* fp = filt + (size_t)d * 8192;
    float2 p[32];
#pragma unroll
    for (int t = 0; t < 16; ++t) {
      int m = tid + t * NTH;
      p[t] = make_float2(fp[2*m], fp[2*m + 1]);
    }
#pragma unroll
    for (int t = 16; t < 32; ++t) p[t] = make_float2(0.f, 0.f);
    fft5_regs<256, false, true, false>(p, tid);
#pragma unroll
    for (int t = 0; t < 32; ++t) L[swz(tid + t * 256)] = p[t];
  }
  __syncthreads();
  pass5_lds<false>(L, tid);
  __syncthreads();
  pass3_lds<false>(L, tid);
  __syncthreads();
#pragma unroll
  for (int pq = 0; pq < MAXP; ++pq) {
    int k = tid + pq * NTH;
    if (k <= M/2) {
      int rk  = rev13(k);
      int rmk = rev13((M - k) & (M - 1));
      float2 Zk = L[swz(rk)], Zmk = L[swz(rmk)];
      float2 Ze = make_float2(0.5f*(Zk.x + Zmk.x), 0.5f*(Zk.y - Zmk.y));
      float2 t  = make_float2(Zk.x - Zmk.x, Zk.y + Zmk.y);
      float2 Zo = make_float2(0.5f*t.y, -0.5f*t.x);
      float s, c; __sincosf(-PI_F * (float)k * (1.0f/(float)M), &s, &c);
      float2 W = make_float2(c, s);
      float2 WZo = cmul(W, Zo);
      Kk[pq]  = cadd(Ze, WZo);
      Kmk[pq] = conjf2(csub(Ze, WZo));
    }
  }
  __syncthreads();

  {
    const float* xp = x + (size_t)b * (8192 * 1024) + d;
    float2 p[32];
#pragma unroll
    for (int t = 0; t < 16; ++t) {
      int m = tid + t * NTH;
      p[t] = make_float2(xp[(size_t)(2*m)     * 1024],
                         xp[(size_t)(2*m + 1) * 1024]);
    }
#pragma unroll
    for (int t = 16; t < 32; ++t) p[t] = make_float2(0.f, 0.f);
    fft5_regs<256, false, true, false>(p, tid);
#pragma unroll
    for (int t = 0; t < 32; ++t) L[swz(tid + t * 256)] = p[t];
  }
  __syncthreads();
  pass5_lds<false>(L, tid);
  __syncthreads();
  pass3_lds<false>(L, tid);
  __syncthreads();

#pragma unroll
  for (int pq = 0; pq < MAXP; ++pq) {
    int k = tid + pq * NTH;
    if (k <= M/2) {
      int rk  = rev13(k);
      int rmk = rev13((M - k) & (M - 1));
      float2 Zk = L[swz(rk)], Zmk = L[swz(rmk)];
      float2 Ze = make_float2(0.5f*(Zk.x + Zmk.x), 0.5f*(Zk.y - Zmk.y));
      float2 t  = make_float2(Zk.x - Zmk.x, Zk.y + Zmk.y);
      float2 Zo = make_float2(0.5f*t.y, -0.5f*t.x);
      float s, c; __sincosf(-PI_F * (float)k * (1.0f/(float)M), &s, &c);
      float2 W = make_float2(c, s);
      float2 WZo = cmul(W, Zo);
      float2 Uk  = cadd(Ze, WZo);
      float2 Umk = conjf2(csub(Ze, WZo));
      float2 Yk  = cmul(Uk,  Kk[pq]);
      float2 Ymk = cmul(Umk, Kmk[pq]);
      float2 Ye  = make_float2(0.5f*(Yk.x + Ymk.x), 0.5f*(Yk.y - Ymk.y));
      float2 t2  = make_float2(0.5f*(Yk.x - Ymk.x), 0.5f*(Yk.y + Ymk.y));
      float2 Zoy = cmul(conjf2(W), t2);
      float2 Zyk  = make_float2(Ye.x - Zoy.y, Ye.y + Zoy.x);
      float2 Zymk = make_float2(Ye.x + Zoy.y, Zoy.x - Ye.y);
      L[swz(rk)]  = Zyk;
      L[swz(rmk)] = Zymk;
    }
  }
  __syncthreads();

  pass3_lds<true>(L, tid);
  __syncthreads();
  pass5_lds<true>(L, tid);
  __syncthreads();

  {
    float2 p[32];
#pragma unroll
    for (int t = 0; t < 32; ++t) p[t] = L[swz(tid + t * 256)];
    fft5_regs<256, true, false, true>(p, tid);
    float* yp = y + (size_t)b * (8192 * 1024) + d;
    const float inv = 1.0f / (float)M;
#pragma unroll
    for (int t = 0; t < 16; ++t) {
      int m = tid + t * NTH;
      yp[(size_t)(2*m)     * 1024] = p[t].x * inv;
      yp[(size_t)(2*m + 1) * 1024] = p[t].y * inv;
    }
  }
}

extern "C" void kernel_launch(void* const* d_in, const int* in_sizes, int n_in,
                              void* d_out, int out_size, void* d_ws, size_t ws_size,
                              hipStream_t stream) {
  const float* x    = (const float*)d_in[0];   // (b, l, d) fp32
  const float* filt = (const float*)d_in[1];   // (d, l) fp32
  float* y = (float*)d_out;                    // (b, l, d) fp32

  const int D = 1024, Lseq = 8192;
  const int B = in_sizes[0] / (D * Lseq);      // 4

  const size_t kf_bytes = (size_t)D * (M/2 + 1) * sizeof(float4);  // ~67 MB
  dim3 grid(B * D), block(NTH);

  if (d_ws != nullptr && ws_size >= kf_bytes) {
    hipLaunchKernelGGL(filt_fft_kernel, dim3(D), dim3(NTH), 0, stream,
                       filt, (float4*)d_ws);
    hipLaunchKernelGGL(longconv_kf_kernel, grid, block, 0, stream,
                       x, (const float4*)d_ws, y);
  } else {
    hipLaunchKernelGGL(longconv_fallback_kernel, grid, block, 0, stream,
                       x, filt, y);
  }
}

// Round 7
// 610.057 us; speedup vs baseline: 1.5460x; 1.5460x over previous
//
#include <hip/hip_runtime.h>

// FFT-based causal long convolution for (b=4, l=8192, d=1024) fp32.
// One workgroup per (b, d) pair. Real FFT of N=16384 as complex FFT of M=8192
// via even/odd packing. 32 KB LDS batch buffer (half-spectrum at a time).
//
// vs round 6 (spill regression #3):
//  - Occupancy attribute reverted to __launch_bounds__(NTH, 2). Empirical law
//    on this toolchain (r4/r5/r6): VGPR cap ~= 256/min_waves_per_EU. Asking
//    for 4 waves/EU (launch_bounds(.,4) or waves_per_eu(4,4)) forces a
//    64-VGPR allocation and wholesale spill of the ~110-reg live set
//    (1.6-2.5 GB scratch HBM traffic). With min=2 the cap is 128 >= demand,
//    no spill, and HW occupancy is still 4 blocks/CU = 16 waves/CU
//    (min of LDS 160/32=5 and VGPR floor(512/~110)=4 waves/SIMD).
//  - kf stored PARITY-PLANAR: even-k plane kfE[kp]=K(2kp), odd plane
//    kfO[kp]=K(2kp+1). Round-6 batches read every other float4 (32 B
//    stride, 50% line utilization over 536 MB of kf volume). Planar reads
//    are dense 16 B/thread.
//  - Unchanged: register-lean batched pipeline (xv[16]+q1[16], factorized
//    first/last pass), 32 KB LDS middle section, load-in-loop spectral
//    multiply, bijective XCD swizzle, swz() LDS bank swizzle.

#define M 8192
#define NTH 256
#define KFS 2064          // float4 stride per parity plane per d (2049 used)
#define MAXP 17           // fallback kernel only

__device__ __forceinline__ float2 cadd(float2 a, float2 b){ return make_float2(a.x+b.x, a.y+b.y); }
__device__ __forceinline__ float2 csub(float2 a, float2 b){ return make_float2(a.x-b.x, a.y-b.y); }
__device__ __forceinline__ float2 cmul(float2 a, float2 b){ return make_float2(a.x*b.x - a.y*b.y, a.x*b.y + a.y*b.x); }
__device__ __forceinline__ float2 conjf2(float2 a){ return make_float2(a.x, -a.y); }
__device__ __forceinline__ int rev13(int k){ return (int)(__brev((unsigned)k) >> 19); }
__device__ __forceinline__ int swz(int e){ return e ^ ((e >> 4) & 15) ^ ((e >> 8) & 15); }

static __device__ const float PI_F = 3.14159265358979323846f;

// cos/sin(pi*u/16); indexed with compile-time u in fully unrolled loops.
constexpr float CR_C[17] = {
  1.f, 0.98078528f, 0.92387953f, 0.83146961f, 0.70710678f,
  0.55557023f, 0.38268343f, 0.19509032f, 0.f, -0.19509032f,
  -0.38268343f, -0.55557023f, -0.70710678f, -0.83146961f,
  -0.92387953f, -0.98078528f, -1.f };
constexpr float CR_S[17] = {
  0.f, 0.19509032f, 0.38268343f, 0.55557023f, 0.70710678f,
  0.83146961f, 0.92387953f, 0.98078528f, 1.f, 0.98078528f,
  0.92387953f, 0.83146961f, 0.70710678f, 0.55557023f,
  0.38268343f, 0.19509032f, 0.f };

// a * e^{-i*pi*idx/16} (fwd) or a * e^{+i*pi*idx/16} (inv); idx compile-time.
__device__ __forceinline__ float2 cmul_cr(float2 a, int idx, bool inv) {
  if (idx == 0) return a;
  const float c = CR_C[idx], s = CR_S[idx];
  if (!inv) return make_float2(a.x*c + a.y*s, a.y*c - a.x*s);
  return make_float2(a.x*c - a.y*s, a.x*s + a.y*c);
}

// ---------------- 16-point fused 4-stage networks --------------------------
template<bool INV>
__device__ __forceinline__ void fft4_regs(float2 (&p)[16], float2 w0) {
  float2 w[4];
  w[0] = w0;
  w[1] = cmul(w[0], w[0]);
  w[2] = cmul(w[1], w[1]);
  w[3] = cmul(w[2], w[2]);
  if (!INV) {
#pragma unroll
    for (int st = 0; st < 4; ++st) {
      const int D = 8 >> st;
#pragma unroll
      for (int t0 = 0; t0 < 16; ++t0) {
        if ((t0 & D) == 0) {
          const int u = t0 & (D - 1);
          float2 a = p[t0], b = p[t0 + D];
          p[t0] = cadd(a, b);
          p[t0 + D] = cmul_cr(cmul(csub(a, b), w[st]), u * (16 / D), false);
        }
      }
    }
  } else {
#pragma unroll
    for (int st = 0; st < 4; ++st) {
      const int D = 1 << st;
#pragma unroll
      for (int t0 = 0; t0 < 16; ++t0) {
        if ((t0 & D) == 0) {
          const int u = t0 & (D - 1);
          float2 b = cmul_cr(cmul(p[t0 + D], w[3 - st]), u * (16 / D), true);
          float2 a = p[t0];
          p[t0] = cadd(a, b);
          p[t0 + D] = csub(a, b);
        }
      }
    }
  }
}

// Contiguous 16-pt groups (r=0): fwd halves 8..1, inv halves 1..8. No sincos.
template<bool INV>
__device__ __forceinline__ void fft4c_regs(float2 (&p)[16]) {
  if (!INV) {
#pragma unroll
    for (int st = 0; st < 4; ++st) {
      const int D = 8 >> st;
#pragma unroll
      for (int t0 = 0; t0 < 16; ++t0) {
        if ((t0 & D) == 0) {
          const int u = t0 & (D - 1);
          float2 a = p[t0], b = p[t0 + D];
          p[t0] = cadd(a, b);
          p[t0 + D] = cmul_cr(csub(a, b), u * (16 / D), false);
        }
      }
    }
  } else {
#pragma unroll
    for (int st = 0; st < 4; ++st) {
      const int D = 1 << st;
#pragma unroll
      for (int t0 = 0; t0 < 16; ++t0) {
        if ((t0 & D) == 0) {
          const int u = t0 & (D - 1);
          float2 b = cmul_cr(p[t0 + D], u * (16 / D), true);
          float2 a = p[t0];
          p[t0] = cadd(a, b);
          p[t0 + D] = csub(a, b);
        }
      }
    }
  }
}

// Stride-16 pass over the 4096-pt batch buffer. 256 groups = 256 threads.
template<bool INV>
__device__ __forceinline__ void pass_s16(float2* LB, int tid) {
  const int r = tid & 15, gl = tid >> 4;
  const int base = gl * 256 + r;
  float2 q[16];
#pragma unroll
  for (int t = 0; t < 16; ++t) q[t] = LB[swz(base + 16 * t)];
  float s, c;
  const float th = PI_F * (float)r * (1.0f / 128.0f);
  __sincosf(INV ? th : -th, &s, &c);
  fft4_regs<INV>(q, make_float2(c, s));
#pragma unroll
  for (int t = 0; t < 16; ++t) LB[swz(base + 16 * t)] = q[t];
}

// Contiguous pass over the 4096-pt batch buffer. 256 groups = 256 threads.
template<bool INV>
__device__ __forceinline__ void pass_c16(float2* LB, int tid) {
  const int base = tid * 16;
  float2 q[16];
#pragma unroll
  for (int t = 0; t < 16; ++t) q[t] = LB[swz(base + t)];
  fft4c_regs<INV>(q);
#pragma unroll
  for (int t = 0; t < 16; ++t) LB[swz(base + t)] = q[t];
}

// Spectral multiply for one parity batch; kfp = dense parity plane (index kp).
template<int HALF>
__device__ __forceinline__ void spec_mult(float2* LB, int tid,
                                          const float4* kfp) {
  constexpr int NQ = (HALF == 0) ? 9 : 8;
#pragma unroll
  for (int q = 0; q < NQ; ++q) {
    int kp = tid + 256 * q;
    if (HALF == 1 || kp <= 2048) {           // odd plane: kp<=2047 always
      int k = 2 * kp + HALF;
      float4 kv = kfp[kp];                   // dense, short-lived
      int rk  = rev13(k) - HALF * 4096;      // local position in batch
      int rmk = rev13((M - k) & (M - 1)) - HALF * 4096;
      float2 Zk = LB[swz(rk)], Zmk = LB[swz(rmk)];
      float2 Ze = make_float2(0.5f*(Zk.x + Zmk.x), 0.5f*(Zk.y - Zmk.y));
      float2 t  = make_float2(Zk.x - Zmk.x, Zk.y + Zmk.y);
      float2 Zo = make_float2(0.5f*t.y, -0.5f*t.x);
      float s, c; __sincosf(-PI_F * (float)k * (1.0f/(float)M), &s, &c);
      float2 W = make_float2(c, s);
      float2 WZo = cmul(W, Zo);
      float2 Uk  = cadd(Ze, WZo);
      float2 Umk = conjf2(csub(Ze, WZo));
      float2 Yk  = cmul(Uk,  make_float2(kv.x, kv.y));
      float2 Ymk = cmul(Umk, make_float2(kv.z, kv.w));
      float2 Ye  = make_float2(0.5f*(Yk.x + Ymk.x), 0.5f*(Yk.y - Ymk.y));
      float2 t2  = make_float2(0.5f*(Yk.x - Ymk.x), 0.5f*(Yk.y + Ymk.y));
      float2 Zoy = cmul(conjf2(W), t2);
      float2 Zyk  = make_float2(Ye.x - Zoy.y, Ye.y + Zoy.x);
      float2 Zymk = make_float2(Ye.x + Zoy.y, Zoy.x - Ye.y);
      LB[swz(rk)]  = Zyk;
      LB[swz(rmk)] = Zymk;                   // k==0 / k==4096: same slot, same value
    }
  }
}

// Spectrum extract (filter) for one parity batch -> dense parity plane.
template<int HALF>
__device__ __forceinline__ void spec_extract(float2* LB, int tid,
                                             float4* out) {
  constexpr int NQ = (HALF == 0) ? 9 : 8;
#pragma unroll
  for (int q = 0; q < NQ; ++q) {
    int kp = tid + 256 * q;
    if (HALF == 1 || kp <= 2048) {
      int k = 2 * kp + HALF;
      int rk  = rev13(k) - HALF * 4096;
      int rmk = rev13((M - k) & (M - 1)) - HALF * 4096;
      float2 Zk = LB[swz(rk)], Zmk = LB[swz(rmk)];
      float2 Ze = make_float2(0.5f*(Zk.x + Zmk.x), 0.5f*(Zk.y - Zmk.y));
      float2 t  = make_float2(Zk.x - Zmk.x, Zk.y + Zmk.y);
      float2 Zo = make_float2(0.5f*t.y, -0.5f*t.x);
      float s, c; __sincosf(-PI_F * (float)k * (1.0f/(float)M), &s, &c);
      float2 W = make_float2(c, s);
      float2 WZo = cmul(W, Zo);
      float2 Kk = cadd(Ze, WZo);
      float2 Km = conjf2(csub(Ze, WZo));
      out[kp] = make_float4(Kk.x, Kk.y, Km.x, Km.y);
    }
  }
}

// Forward middle: batch data in LB -> spectrum (bit-reversed) in LB.
__device__ __forceinline__ void fwd_middle(float2* LB, int tid) {
  pass_s16<false>(LB, tid);                  // halves 128..16
  __syncthreads();
  pass_c16<false>(LB, tid);                  // halves 8..1
  __syncthreads();
}

// Inverse middle: spectrum in LB -> batch data in LB.
__device__ __forceinline__ void inv_middle(float2* LB, int tid) {
  pass_c16<true>(LB, tid);                   // halves 1..8
  __syncthreads();
  pass_s16<true>(LB, tid);                   // halves 16..128
  __syncthreads();
}

// Precompute per-d filter spectrum into parity planes.
__global__ __launch_bounds__(NTH, 2)
void filt_fft_kernel(const float* __restrict__ filt, float4* __restrict__ kf) {
  __shared__ float2 LB[4096];                // 32 KB
  const int tid = threadIdx.x;
  const int d = blockIdx.x;
  const int D = gridDim.x;                   // 1024
  const float* fp = filt + (size_t)d * 8192;
  float4* outE = kf + (size_t)d * KFS;                   // even plane
  float4* outO = kf + (size_t)(D + d) * KFS;             // odd plane

  float2 xv[16];
#pragma unroll
  for (int t = 0; t < 16; ++t) {
    int m = tid + t * NTH;
    xv[t] = make_float2(fp[2*m], fp[2*m + 1]);
  }
  float s, c;
  __sincosf(-PI_F * (float)tid * (1.0f / 4096.0f), &s, &c);
  const float2 w0f = make_float2(c, s);
  const float2 w0fsq = cmul(w0f, w0f);

  // ---- batch 1 (odd k, upper half): q = xv * w0f * cr(t), then 4 stages ---
  {
    float2 q[16];
#pragma unroll
    for (int t = 0; t < 16; ++t) q[t] = cmul_cr(cmul(xv[t], w0f), t, false);
    fft4_regs<false>(q, w0fsq);
#pragma unroll
    for (int g = 0; g < 16; ++g) LB[swz(g * 256 + tid)] = q[g];
  }
  __syncthreads();
  fwd_middle(LB, tid);
  spec_extract<1>(LB, tid, outO);
  __syncthreads();

  // ---- batch 0 (even k, lower half): xv in place ----
  fft4_regs<false>(xv, w0fsq);
#pragma unroll
  for (int g = 0; g < 16; ++g) LB[swz(g * 256 + tid)] = xv[g];
  __syncthreads();
  fwd_middle(LB, tid);
  spec_extract<0>(LB, tid, outE);
}

// ---------------- HOT KERNEL: requires kf ----------------------------------
__global__ __launch_bounds__(NTH, 2)
void longconv_kf_kernel(const float* __restrict__ x,
                        const float4* __restrict__ kf,
                        float* __restrict__ y) {
  __shared__ float2 LB[4096];                // 32 KB
  const int tid = threadIdx.x;

  // Bijective XCD swizzle: XCD j owns 512 consecutive blk -> co-resident
  // blocks share x/y cache lines in its private L2.
  const int nwg = gridDim.x;                 // 4096, multiple of 8
  const int cpx = nwg >> 3;
  const int bid = blockIdx.x;
  const int blk = (bid & 7) * cpx + (bid >> 3);
  const int d = blk & 1023;
  const int b = blk >> 10;

  const float4* kfpE = kf + (size_t)d * KFS;             // even plane
  const float4* kfpO = kf + (size_t)(1024 + d) * KFS;    // odd plane

  // ---- load x (strided 4B/4KB; lines merged across blocks in L2) ----------
  float2 xv[16];
  {
    const float* xp = x + (size_t)b * (8192 * 1024) + d;
#pragma unroll
    for (int t = 0; t < 16; ++t) {
      int m = tid + t * NTH;
      xv[t] = make_float2(xp[(size_t)(2*m)     * 1024],
                          xp[(size_t)(2*m + 1) * 1024]);
    }
  }
  float s, c;
  __sincosf(-PI_F * (float)tid * (1.0f / 4096.0f), &s, &c);
  const float2 w0f = make_float2(c, s);
  const float2 w0fsq = cmul(w0f, w0f);

  // ---- batch 1 (odd k, upper half) first: q built from xv, xv persists ----
  float2 q1[16];
#pragma unroll
  for (int t = 0; t < 16; ++t) q1[t] = cmul_cr(cmul(xv[t], w0f), t, false);
  fft4_regs<false>(q1, w0fsq);
#pragma unroll
  for (int g = 0; g < 16; ++g) LB[swz(g * 256 + tid)] = q1[g];
  __syncthreads();
  fwd_middle(LB, tid);
  spec_mult<1>(LB, tid, kfpO);
  __syncthreads();
  inv_middle(LB, tid);
#pragma unroll
  for (int g = 0; g < 16; ++g) q1[g] = LB[swz(g * 256 + tid)];
  __syncthreads();                           // LB reads done before batch 0

  // ---- batch 0 (even k, lower half): xv consumed in place -----------------
  fft4_regs<false>(xv, w0fsq);
#pragma unroll
  for (int g = 0; g < 16; ++g) LB[swz(g * 256 + tid)] = xv[g];
  __syncthreads();
  fwd_middle(LB, tid);
  spec_mult<0>(LB, tid, kfpE);
  __syncthreads();
  inv_middle(LB, tid);
#pragma unroll
  for (int g = 0; g < 16; ++g) xv[g] = LB[swz(g * 256 + tid)];

  // ---- final inverse (halves 256..4096) + recombine + store y -------------
  {
    float si, ci;
    __sincosf(PI_F * (float)tid * (1.0f / 4096.0f), &si, &ci);
    const float2 w0i = make_float2(ci, si);
    const float2 w0isq = cmul(w0i, w0i);
    fft4_regs<true>(xv, w0isq);              // lower-half inverse stages
    fft4_regs<true>(q1, w0isq);              // upper-half inverse stages
    float* yp = y + (size_t)b * (8192 * 1024) + d;
    const float inv = 1.0f / (float)M;
#pragma unroll
    for (int t = 0; t < 16; ++t) {
      // final stage (D=16): lower output only (upper not needed for y)
      float2 bq = cmul_cr(cmul(q1[t], w0i), t, true);
      float2 v = cadd(xv[t], bq);
      int m = tid + t * NTH;                 // first l samples (packed pairs)
      yp[(size_t)(2*m)     * 1024] = v.x * inv;
      yp[(size_t)(2*m + 1) * 1024] = v.y * inv;
    }
  }
}

// ---------------- FALLBACK: no workspace (64 KB LDS, round-4 structure) ----
template<int HS, bool INV, bool FIRST_PAD, bool LAST_HALF>
__device__ __forceinline__ void fft5_regs(float2 (&p)[32], int r) {
  float s, c;
  const float th = PI_F * (float)r * (1.0f / (16.0f * (float)HS));
  __sincosf(INV ? th : -th, &s, &c);
  float2 w[5];
  w[0] = make_float2(c, s);
  w[1] = cmul(w[0], w[0]);
  w[2] = cmul(w[1], w[1]);
  w[3] = cmul(w[2], w[2]);
  w[4] = cmul(w[3], w[3]);
  if (!INV) {
#pragma unroll
    for (int st = 0; st < 5; ++st) {
      const int D = 16 >> st;
#pragma unroll
      for (int t0 = 0; t0 < 32; ++t0) {
        if ((t0 & D) == 0) {
          const int u = t0 & (D - 1);
          float2 a = p[t0];
          if (FIRST_PAD && st == 0) {
            p[t0 + D] = cmul_cr(cmul(a, w[0]), u, false);
          } else {
            float2 b = p[t0 + D];
            p[t0] = cadd(a, b);
            p[t0 + D] = cmul_cr(cmul(csub(a, b), w[st]), u * (16 / D), false);
          }
        }
      }
    }
  } else {
#pragma unroll
    for (int st = 0; st < 5; ++st) {
      const int D = 1 << st;
#pragma unroll
      for (int t0 = 0; t0 < 32; ++t0) {
        if ((t0 & D) == 0) {
          const int u = t0 & (D - 1);
          float2 b = cmul_cr(cmul(p[t0 + D], w[4 - st]), u * (16 / D), true);
          float2 a = p[t0];
          p[t0] = cadd(a, b);
          if (!(LAST_HALF && st == 4)) p[t0 + D] = csub(a, b);
        }
      }
    }
  }
}

template<bool INV>
__device__ __forceinline__ void pass5_lds(float2* L, int tid) {
  const int r = tid & 7;
  const int base = ((tid - r) << 5) + r;
  float2 p[32];
#pragma unroll
  for (int t = 0; t < 32; ++t) p[t] = L[swz(base + t * 8)];
  fft5_regs<8, INV, false, false>(p, r);
#pragma unroll
  for (int t = 0; t < 32; ++t) L[swz(base + t * 8)] = p[t];
}

template<bool INV>
__device__ __forceinline__ void pass3_lds(float2* L, int tid) {
#pragma unroll
  for (int g = 0; g < 4; ++g) {
    const int base = tid * 32 + g * 8;
    float2 p[8];
#pragma unroll
    for (int t = 0; t < 8; ++t) p[t] = L[swz(base + t)];
    if (!INV) {
#pragma unroll
      for (int st = 0; st < 3; ++st) {
        const int D = 4 >> st;
#pragma unroll
        for (int t0 = 0; t0 < 8; ++t0) {
          if ((t0 & D) == 0) {
            const int u = t0 & (D - 1);
            float2 a = p[t0], b = p[t0 + D];
            p[t0] = cadd(a, b);
            p[t0 + D] = cmul_cr(csub(a, b), u * (16 / D), false);
          }
        }
      }
    } else {
#pragma unroll
      for (int st = 0; st < 3; ++st) {
        const int D = 1 << st;
#pragma unroll
        for (int t0 = 0; t0 < 8; ++t0) {
          if ((t0 & D) == 0) {
            const int u = t0 & (D - 1);
            float2 b = cmul_cr(p[t0 + D], u * (16 / D), true);
            float2 a = p[t0];
            p[t0] = cadd(a, b);
            p[t0 + D] = csub(a, b);
          }
        }
      }
    }
#pragma unroll
    for (int t = 0; t < 8; ++t) L[swz(base + t)] = p[t];
  }
}

__global__ __launch_bounds__(NTH, 2)
void longconv_fallback_kernel(const float* __restrict__ x,
                              const float* __restrict__ filt,
                              float* __restrict__ y) {
  __shared__ float2 L[M];
  const int tid = threadIdx.x;
  const int nwg = gridDim.x;
  const int cpx = nwg >> 3;
  const int bid = blockIdx.x;
  const int blk = (bid & 7) * cpx + (bid >> 3);
  const int d = blk & 1023;
  const int b = blk >> 10;

  float2 Kk[MAXP], Kmk[MAXP];

  {
    const float* fp = filt + (size_t)d * 8192;
    float2 p[32];
#pragma unroll
    for (int t = 0; t < 16; ++t) {
      int m = tid + t * NTH;
      p[t] = make_float2(fp[2*m], fp[2*m + 1]);
    }
#pragma unroll
    for (int t = 16; t < 32; ++t) p[t] = make_float2(0.f, 0.f);
    fft5_regs<256, false, true, false>(p, tid);
#pragma unroll
    for (int t = 0; t < 32; ++t) L[swz(tid + t * 256)] = p[t];
  }
  __syncthreads();
  pass5_lds<false>(L, tid);
  __syncthreads();
  pass3_lds<false>(L, tid);
  __syncthreads();
#pragma unroll
  for (int pq = 0; pq < MAXP; ++pq) {
    int k = tid + pq * NTH;
    if (k <= M/2) {
      int rk  = rev13(k);
      int rmk = rev13((M - k) & (M - 1));
      float2 Zk = L[swz(rk)], Zmk = L[swz(rmk)];
      float2 Ze = make_float2(0.5f*(Zk.x + Zmk.x), 0.5f*(Zk.y - Zmk.y));
      float2 t  = make_float2(Zk.x - Zmk.x, Zk.y + Zmk.y);
      float2 Zo = make_float2(0.5f*t.y, -0.5f*t.x);
      float s, c; __sincosf(-PI_F * (float)k * (1.0f/(float)M), &s, &c);
      float2 W = make_float2(c, s);
      float2 WZo = cmul(W, Zo);
      Kk[pq]  = cadd(Ze, WZo);
      Kmk[pq] = conjf2(csub(Ze, WZo));
    }
  }
  __syncthreads();

  {
    const float* xp = x + (size_t)b * (8192 * 1024) + d;
    float2 p[32];
#pragma unroll
    for (int t = 0; t < 16; ++t) {
      int m = tid + t * NTH;
      p[t] = make_float2(xp[(size_t)(2*m)     * 1024],
                         xp[(size_t)(2*m + 1) * 1024]);
    }
#pragma unroll
    for (int t = 16; t < 32; ++t) p[t] = make_float2(0.f, 0.f);
    fft5_regs<256, false, true, false>(p, tid);
#pragma unroll
    for (int t = 0; t < 32; ++t) L[swz(tid + t * 256)] = p[t];
  }
  __syncthreads();
  pass5_lds<false>(L, tid);
  __syncthreads();
  pass3_lds<false>(L, tid);
  __syncthreads();

#pragma unroll
  for (int pq = 0; pq < MAXP; ++pq) {
    int k = tid + pq * NTH;
    if (k <= M/2) {
      int rk  = rev13(k);
      int rmk = rev13((M - k) & (M - 1));
      float2 Zk = L[swz(rk)], Zmk = L[swz(rmk)];
      float2 Ze = make_float2(0.5f*(Zk.x + Zmk.x), 0.5f*(Zk.y - Zmk.y));
      float2 t  = make_float2(Zk.x - Zmk.x, Zk.y + Zmk.y);
      float2 Zo = make_float2(0.5f*t.y, -0.5f*t.x);
      float s, c; __sincosf(-PI_F * (float)k * (1.0f/(float)M), &s, &c);
      float2 W = make_float2(c, s);
      float2 WZo = cmul(W, Zo);
      float2 Uk  = cadd(Ze, WZo);
      float2 Umk = conjf2(csub(Ze, WZo));
      float2 Yk  = cmul(Uk,  Kk[pq]);
      float2 Ymk = cmul(Umk, Kmk[pq]);
      float2 Ye  = make_float2(0.5f*(Yk.x + Ymk.x), 0.5f*(Yk.y - Ymk.y));
      float2 t2  = make_float2(0.5f*(Yk.x - Ymk.x), 0.5f*(Yk.y + Ymk.y));
      float2 Zoy = cmul(conjf2(W), t2);
      float2 Zyk  = make_float2(Ye.x - Zoy.y, Ye.y + Zoy.x);
      float2 Zymk = make_float2(Ye.x + Zoy.y, Zoy.x - Ye.y);
      L[swz(rk)]  = Zyk;
      L[swz(rmk)] = Zymk;
    }
  }
  __syncthreads();

  pass3_lds<true>(L, tid);
  __syncthreads();
  pass5_lds<true>(L, tid);
  __syncthreads();

  {
    float2 p[32];
#pragma unroll
    for (int t = 0; t < 32; ++t) p[t] = L[swz(tid + t * 256)];
    fft5_regs<256, true, false, true>(p, tid);
    float* yp = y + (size_t)b * (8192 * 1024) + d;
    const float inv = 1.0f / (float)M;
#pragma unroll
    for (int t = 0; t < 16; ++t) {
      int m = tid + t * NTH;
      yp[(size_t)(2*m)     * 1024] = p[t].x * inv;
      yp[(size_t)(2*m + 1) * 1024] = p[t].y * inv;
    }
  }
}

extern "C" void kernel_launch(void* const* d_in, const int* in_sizes, int n_in,
                              void* d_out, int out_size, void* d_ws, size_t ws_size,
                              hipStream_t stream) {
  const float* x    = (const float*)d_in[0];   // (b, l, d) fp32
  const float* filt = (const float*)d_in[1];   // (d, l) fp32
  float* y = (float*)d_out;                    // (b, l, d) fp32

  const int D = 1024, Lseq = 8192;
  const int B = in_sizes[0] / (D * Lseq);      // 4

  const size_t kf_bytes = (size_t)2 * D * KFS * sizeof(float4);  // ~67.6 MB
  dim3 grid(B * D), block(NTH);

  if (d_ws != nullptr && ws_size >= kf_bytes) {
    hipLaunchKernelGGL(filt_fft_kernel, dim3(D), dim3(NTH), 0, stream,
                       filt, (float4*)d_ws);
    hipLaunchKernelGGL(longconv_kf_kernel, grid, block, 0, stream,
                       x, (const float4*)d_ws, y);
  } else {
    hipLaunchKernelGGL(longconv_fallback_kernel, grid, block, 0, stream,
                       x, filt, y);
  }
}